// Round 2
// baseline (251.029 us; speedup 1.0000x reference)
//
#include <hip/hip_runtime.h>

// Problem constants (fixed by the reference)
constexpr int C_ = 2048;
constexpr int H_ = 16;
constexpr int W_ = 16;
constexpr int F_ = 64;
constexpr int P_ = 256;   // samples per complex

// Direct-gather version: no LDS map staging. The 4x texel reuse is served by
// L1/L2 (map[c] = 64 KB; XCD swizzle keeps ~16 live complexes = 1 MB per XCD L2).
// 32768 blocks x 256 threads; each thread produces one float4 of output:
//   block -> (complex c, sample-group sub of 16 samples)
//   thread -> sample s = sub*16 + (tid>>4), feature chunk f = tid&15
// Each texel load: 16 lanes x 16 B = 256 B contiguous. Store: 1 KB/wave contiguous.
__global__ __launch_bounds__(256) void ngf_gather_kernel(
    const float* __restrict__ map_,
    const float* __restrict__ u_,
    const float* __restrict__ v_,
    float* __restrict__ out_) {
  const int g   = blockIdx.x;          // 0..32767
  // XCD swizzle: dispatch round-robins blocks over 8 XCDs (heuristic, perf-only).
  // Complex c's 16 sub-blocks all share g%8 -> same XCD -> map[c] stays in that L2.
  const int xcd = g & 7;
  const int q   = g >> 3;              // 0..4095
  const int c   = (xcd << 8) | (q >> 4);  // 0..2047
  const int sub = q & 15;              // sample group 0..15

  const int tid = threadIdx.x;
  const int f   = tid & 15;            // float4 chunk along feature dim
  const int s   = (sub << 4) | (tid >> 4); // sample 0..255

  const float x = u_[c * P_ + s] * (float)(W_ - 1);
  const float y = v_[c * P_ + s] * (float)(H_ - 1);
  // u,v in [0,1] -> x,y in [0,15]; trunc == floor, only upper clamp needed.
  int x0 = (int)x; x0 = x0 > W_ - 2 ? W_ - 2 : x0;
  int y0 = (int)y; y0 = y0 > H_ - 2 ? H_ - 2 : y0;
  const float fx = x - (float)x0;
  const float fy = y - (float)y0;

  // map as float4: per complex 4096, per row 256, per texel 16.
  const float4* base = (const float4*)map_ + (((size_t)c) << 12)
                     + (y0 * W_ + x0) * (F_ / 4) + f;
  const float4 g00 = base[0];
  const float4 g01 = base[F_ / 4];           // x0+1
  const float4 g10 = base[W_ * (F_ / 4)];    // y0+1
  const float4 g11 = base[(W_ + 1) * (F_ / 4)];

  const float wx1 = fx, wx0 = 1.0f - fx;
  const float wy1 = fy, wy0 = 1.0f - fy;

  float4 r;
  r.x = (g00.x * wx0 + g01.x * wx1) * wy0 + (g10.x * wx0 + g11.x * wx1) * wy1;
  r.y = (g00.y * wx0 + g01.y * wx1) * wy0 + (g10.y * wx0 + g11.y * wx1) * wy1;
  r.z = (g00.z * wx0 + g01.z * wx1) * wy0 + (g10.z * wx0 + g11.z * wx1) * wy1;
  r.w = (g00.w * wx0 + g01.w * wx1) * wy0 + (g10.w * wx0 + g11.w * wx1) * wy1;

  ((float4*)out_)[(((size_t)c) << 12) + s * (F_ / 4) + f] = r;
}

extern "C" void kernel_launch(void* const* d_in, const int* in_sizes, int n_in,
                              void* d_out, int out_size, void* d_ws, size_t ws_size,
                              hipStream_t stream) {
  const float* map_ = (const float*)d_in[0];
  const float* u_   = (const float*)d_in[1];
  const float* v_   = (const float*)d_in[2];
  float* out_ = (float*)d_out;

  const int blocks = C_ * (P_ / 16);  // 2048 * 16 = 32768
  ngf_gather_kernel<<<blocks, 256, 0, stream>>>(map_, u_, v_, out_);
}

// Round 3
// 247.843 us; speedup vs baseline: 1.0129x; 1.0129x over previous
//
#include <hip/hip_runtime.h>

// Problem constants (fixed by the reference)
constexpr int C_ = 2048;
constexpr int H_ = 16;
constexpr int W_ = 16;
constexpr int F_ = 64;
constexpr int P_ = 256;   // samples per complex
constexpr int K_ = 2;     // samples per thread (MLP batching)

// Latency-bound fix: batch K=2 samples per thread so each wave has 8 texel
// loads (+2 u/v pairs) in flight before any consumption. __launch_bounds__
// (256,8) pins VGPR<=64 -> 8 waves/SIMD -> 32 waves/CU.
// Grid: 16384 blocks; block -> (complex c, 32-sample chunk sub).
// Thread: f = tid&15 (float4 feature chunk), sg = tid>>4 (0..15);
// samples s0 = sub*32+sg and s0+16.
// Texel load: 16 lanes x 16 B = 256 B contiguous per sample-group.
// Store: wave writes 1 KB contiguous (4 consecutive sample-groups x 16 f).
__global__ __launch_bounds__(256, 8) void ngf_gather2_kernel(
    const float* __restrict__ map_,
    const float* __restrict__ u_,
    const float* __restrict__ v_,
    float* __restrict__ out_) {
  const int g   = blockIdx.x;          // 0..16383
  // XCD swizzle: each complex's 8 blocks land on one XCD (perf heuristic only).
  const int xcd = g & 7;
  const int q   = g >> 3;              // 0..2047
  const int c   = (xcd << 8) | (q >> 3);  // 0..2047
  const int sub = q & 7;               // 32-sample chunk

  const int tid = threadIdx.x;
  const int f   = tid & 15;            // float4 chunk along feature dim
  const int sg  = tid >> 4;            // 0..15
  const int s0  = sub * 32 + sg;       // samples s0 + 16*k, k=0..K-1

  const float* uc = u_ + c * P_ + s0;
  const float* vc = v_ + c * P_ + s0;

  // ---- issue all u/v loads ----
  float uu[K_], vv[K_];
#pragma unroll
  for (int k = 0; k < K_; ++k) { uu[k] = uc[k * 16]; vv[k] = vc[k * 16]; }

  const float4* cmap = (const float4*)map_ + (((size_t)c) << 12) + f;

  // ---- issue all texel loads before consuming any ----
  float4 t00[K_], t01[K_], t10[K_], t11[K_];
  float fx[K_], fy[K_];
#pragma unroll
  for (int k = 0; k < K_; ++k) {
    const float x = uu[k] * (float)(W_ - 1);
    const float y = vv[k] * (float)(H_ - 1);
    // u,v in [0,1) -> x,y in [0,15); trunc == floor; clamp is belt+braces.
    int x0 = (int)x; x0 = x0 > W_ - 2 ? W_ - 2 : x0;
    int y0 = (int)y; y0 = y0 > H_ - 2 ? H_ - 2 : y0;
    fx[k] = x - (float)x0;
    fy[k] = y - (float)y0;
    const float4* b = cmap + (y0 * W_ + x0) * (F_ / 4);
    t00[k] = b[0];
    t01[k] = b[F_ / 4];                // x0+1
    t10[k] = b[W_ * (F_ / 4)];         // y0+1
    t11[k] = b[(W_ + 1) * (F_ / 4)];   // y0+1, x0+1
  }

  // ---- lerp + store ----
  float4* gout = (float4*)out_ + (((size_t)c) << 12) + f;
#pragma unroll
  for (int k = 0; k < K_; ++k) {
    const int s = s0 + k * 16;
    const float wx1 = fx[k], wx0 = 1.0f - wx1;
    const float wy1 = fy[k], wy0 = 1.0f - wy1;
    float4 r;
    r.x = (t00[k].x * wx0 + t01[k].x * wx1) * wy0 + (t10[k].x * wx0 + t11[k].x * wx1) * wy1;
    r.y = (t00[k].y * wx0 + t01[k].y * wx1) * wy0 + (t10[k].y * wx0 + t11[k].y * wx1) * wy1;
    r.z = (t00[k].z * wx0 + t01[k].z * wx1) * wy0 + (t10[k].z * wx0 + t11[k].z * wx1) * wy1;
    r.w = (t00[k].w * wx0 + t01[k].w * wx1) * wy0 + (t10[k].w * wx0 + t11[k].w * wx1) * wy1;
    gout[s * (F_ / 4)] = r;
  }
}

extern "C" void kernel_launch(void* const* d_in, const int* in_sizes, int n_in,
                              void* d_out, int out_size, void* d_ws, size_t ws_size,
                              hipStream_t stream) {
  const float* map_ = (const float*)d_in[0];
  const float* u_   = (const float*)d_in[1];
  const float* v_   = (const float*)d_in[2];
  float* out_ = (float*)d_out;

  const int blocks = C_ * P_ / (16 * K_);  // 2048*256/32 = 16384
  ngf_gather2_kernel<<<blocks, 256, 0, stream>>>(map_, u_, v_, out_);
}